// Round 8
// baseline (103.127 us; speedup 1.0000x reference)
//
#include <hip/hip_runtime.h>

typedef __attribute__((ext_vector_type(8))) short short8;
typedef __attribute__((ext_vector_type(4))) float f32x4;
typedef unsigned int u32;

#define NB 64
#define NC 3
#define NH 384
#define NW 384
#define HW (NH*NW)
#define NPATCH 576
#define NE 768
#define KDIM 768           // NC*16*16
#define MDIM (NB*NPATCH)   // 36864

#define BM 128
#define BN 256
#define BK 64
#define NBLK_N (NE / BN)       // 3
#define NBLK_M (MDIM / BM)     // 288
#define NWG (NBLK_M * NBLK_N)  // 864
#define NKK (KDIM / BK)        // 12

#define TILE_A_BYTES (BM * BK * 2)                   // 16384
#define TILE_B_BYTES (BN * BK * 2)                   // 32768
#define WS_A_BYTES ((size_t)NBLK_M * NKK * TILE_A_BYTES)  // 56,623,104
#define WS_B_BYTES ((size_t)NBLK_N * NKK * TILE_B_BYTES)  // 1,179,648

#define GLOBAL_AS __attribute__((address_space(1)))
#define LDS_AS    __attribute__((address_space(3)))

__device__ __forceinline__ unsigned short f2bf(float f) {
    unsigned int u = __builtin_bit_cast(unsigned int, f);
    u += 0x7fffu + ((u >> 16) & 1u);   // round-to-nearest-even
    return (unsigned short)(u >> 16);
}

// packed f32x2 -> bf16x2 (RNE), 1 VALU inst (no builtin on gfx950)
__device__ __forceinline__ u32 cvtpk(float lo, float hi) {
    u32 r;
    asm("v_cvt_pk_bf16_f32 %0, %1, %2" : "=v"(r) : "v"(lo), "v"(hi));
    return r;
}

__device__ __forceinline__ void gload_lds16(const void* g, void* l) {
    __builtin_amdgcn_global_load_lds((const GLOBAL_AS u32*)g, (LDS_AS u32*)l, 16, 0, 0);
}

// =====================================================================
// PASS 1: gather patches -> bf16 A-tile images (XOR swizzle baked in).
// Tile (bm,kk) = 16KB: row r (=m&127) is 64 bf16 (128B); 16B chunk ch
// stored at byte r*128 + ((ch ^ (r&7))*16).  Thread = (m, 8-float chunk).
// =====================================================================
__global__ __launch_bounds__(256) void gather_a(
    const float* __restrict__ x,
    const int* __restrict__ start_h,
    const int* __restrict__ start_w,
    unsigned char* __restrict__ wsa)
{
    int id = blockIdx.x * 256 + threadIdx.x;   // 36864*96 = 3,538,944
    int m  = id / 96;
    int ck = id - m * 96;          // global 8-wide k-chunk 0..95
    int b  = m / NPATCH;
    int n  = m - b * NPATCH;
    int base = b * (NC * HW) + start_h[b * NPATCH + n] * NW
             + start_w[b * NPATCH + n];

    int gk = ck * 8;               // k = c*256 + h*16 + w
    int c  = gk >> 8;
    int h  = (gk & 255) >> 4;
    int w  = gk & 15;              // 0 or 8
    const float* src = x + base + c * HW + h * NW + w;
    float4 f0 = *reinterpret_cast<const float4*>(src);
    float4 f1 = *reinterpret_cast<const float4*>(src + 4);

    int bm = m >> 7, r = m & 127, kk = ck >> 3, ch = ck & 7;
    size_t off = (size_t)(bm * NKK + kk) * TILE_A_BYTES
               + r * 128 + ((ch ^ (r & 7)) * 16);
    *reinterpret_cast<uint4*>(wsa + off) = make_uint4(
        cvtpk(f0.x, f0.y), cvtpk(f0.z, f0.w),
        cvtpk(f1.x, f1.y), cvtpk(f1.z, f1.w));
}

// =====================================================================
// pre-pass (two-pass B): proj_w -> bf16 FRAGMENT-ORDER tiles.
// Tile (bn,kk) = 32KB, 2048 slots of 16B. f = slot>>6 (0..31), l = slot&63:
// holds pw[e = bn*256 + (f>>1)*16 + (l&15)][k = kk*64 + (f&1)*32 + (l>>4)*8 ..+8]
// =====================================================================
__global__ __launch_bounds__(256) void convert_w_frag(
    const float* __restrict__ pw, unsigned char* __restrict__ wsb)
{
    int id = blockIdx.x * 256 + threadIdx.x;   // 36 tiles * 2048 = 73728
    int tile = id >> 11;
    int s    = id & 2047;
    int bn = tile / NKK;
    int kk = tile - bn * NKK;
    int f = s >> 6, l = s & 63;
    int e = bn * 256 + (f >> 1) * 16 + (l & 15);
    int k = kk * 64 + (f & 1) * 32 + (l >> 4) * 8;

    const float4 f0 = *reinterpret_cast<const float4*>(pw + (size_t)e * KDIM + k);
    const float4 f1 = *reinterpret_cast<const float4*>(pw + (size_t)e * KDIM + k + 4);
    *reinterpret_cast<uint4*>(wsb + (size_t)tile * TILE_B_BYTES + s * 16) =
        make_uint4(cvtpk(f0.x, f0.y), cvtpk(f0.z, f0.w),
                   cvtpk(f1.x, f1.y), cvtpk(f1.z, f1.w));
}

// =====================================================================
// PASS 2: dense GEMM. A via global_load_lds (linear, pre-swizzled),
// double-buffered; B fragments in registers; counted-vmcnt barriers.
// =====================================================================
__global__ __launch_bounds__(512, 4) void gemm2(
    const unsigned char* __restrict__ wsa,
    const unsigned char* __restrict__ wsb,
    const float* __restrict__ pb,
    float* __restrict__ out)
{
    __shared__ __align__(16) unsigned short lA[2][BM * BK];  // 2 x 16 KB

    const int tid = threadIdx.x;
    const int bid  = blockIdx.x;
    const int lbid = (bid & 7) * (NWG / 8) + (bid >> 3);   // XCD swizzle
    const int bm = lbid / NBLK_N;
    const int bn = lbid - bm * NBLK_N;
    const int m0 = bm * BM;
    const int e0 = bn * BN;

    const int lane = tid & 63;
    const int wv   = tid >> 6;       // wave 0..7
    const int wr   = wv >> 2;        // 0..1  (64 m-rows)
    const int wc   = wv & 3;         // 0..3  (64 e-cols)
    const int lr   = lane & 15;
    const int lk   = lane >> 4;      // 0..3

    const unsigned char* atiles = wsa + (size_t)bm * NKK * TILE_A_BYTES;
    const unsigned char* btiles = wsb + (size_t)bn * NKK * TILE_B_BYTES;
    unsigned char* lab = reinterpret_cast<unsigned char*>(&lA[0][0]);

    // A-fragment LDS byte offsets (without ks term)
    int ard[4];
    #pragma unroll
    for (int mi = 0; mi < 4; ++mi) {
        int row = wr * 64 + mi * 16 + lr;
        ard[mi] = row * 128;
    }
    const int arow7[4] = { (wr*64+0*16+lr) & 7, (wr*64+1*16+lr) & 7,
                           (wr*64+2*16+lr) & 7, (wr*64+3*16+lr) & 7 };

    uint4 br[8];            // B fragments for current kk: [ks*4+ni]
    f32x4 acc[4][4] = {};

#define STAGEA(KK, BUF)                                                       \
    {                                                                         \
        const unsigned char* s_ = atiles + (size_t)(KK) * TILE_A_BYTES        \
                                + wv * 2048 + lane * 16;                      \
        unsigned char* d_ = lab + (BUF) * 16384 + wv * 2048;                  \
        gload_lds16(s_, d_);                                                  \
        gload_lds16(s_ + 1024, d_ + 1024);                                    \
    }

#define LOADB(KK)                                                             \
    {                                                                         \
        const unsigned char* bt = btiles + (size_t)(KK) * TILE_B_BYTES        \
                                + lane * 16;                                  \
        _Pragma("unroll")                                                     \
        for (int f = 0; f < 8; ++f)                                           \
            br[(f & 1) * 4 + (f >> 1)] = *reinterpret_cast<const uint4*>(     \
                bt + ((wc * 4 + (f >> 1)) * 2 + (f & 1)) * 1024);             \
    }

#define COMPUTE(BUF)                                                          \
    {                                                                         \
        _Pragma("unroll")                                                     \
        for (int ks = 0; ks < 2; ++ks) {                                      \
            short8 af[4];                                                     \
            _Pragma("unroll")                                                 \
            for (int mi = 0; mi < 4; ++mi)                                    \
                af[mi] = *reinterpret_cast<const short8*>(                    \
                    lab + (BUF) * 16384 + ard[mi]                             \
                        + (((ks * 4 + lk) ^ arow7[mi]) * 16));                \
            _Pragma("unroll")                                                 \
            for (int mi = 0; mi < 4; ++mi)                                    \
                _Pragma("unroll")                                             \
                for (int ni = 0; ni < 4; ++ni)                                \
                    acc[mi][ni] = __builtin_amdgcn_mfma_f32_16x16x32_bf16(    \
                        af[mi], __builtin_bit_cast(short8, br[ks * 4 + ni]),  \
                        acc[mi][ni], 0, 0, 0);                                \
        }                                                                     \
    }

    // prologue: A(0)->buf0, A(1)->buf1 in flight; B(0) in flight to regs
    STAGEA(0, 0)
    STAGEA(1, 1)
    LOADB(0)
    __builtin_amdgcn_sched_barrier(0);
    asm volatile("s_waitcnt vmcnt(8)" ::: "memory");   // A(0)+A(1) arrived
    __builtin_amdgcn_sched_barrier(0);
    __builtin_amdgcn_s_barrier();

    #pragma unroll
    for (int kk = 0; kk < NKK; ++kk) {
        const int buf = kk & 1;
        COMPUTE(buf)                       // reads lA[buf] + br(kk)
        if (kk + 1 < NKK) LOADB(kk + 1)    // br free after compute (WAR ok)
        if (kk + 1 < NKK) {
            __builtin_amdgcn_sched_barrier(0);
            __builtin_amdgcn_s_barrier();          // all waves done w/ lA[buf]
            __builtin_amdgcn_sched_barrier(0);
            if (kk + 2 < NKK) STAGEA(kk + 2, buf)  // DMA into freed buffer
            __builtin_amdgcn_sched_barrier(0);
            // wait A(kk+1) (oldest in queue) retired; newer loads stay in flight
            if (kk + 2 < NKK) {
                asm volatile("s_waitcnt vmcnt(10)" ::: "memory");
            } else {
                asm volatile("s_waitcnt vmcnt(8)" ::: "memory");
            }
            __builtin_amdgcn_sched_barrier(0);
            __builtin_amdgcn_s_barrier();          // lA[buf^1] ready for all
            __builtin_amdgcn_sched_barrier(0);
        }
    }

#undef STAGEA
#undef LOADB
#undef COMPUTE

    // ---- epilogue: bias + store ----
    float biasv[4];
    #pragma unroll
    for (int ni = 0; ni < 4; ++ni)
        biasv[ni] = pb[e0 + wc * 64 + ni * 16 + lr];

    #pragma unroll
    for (int mi = 0; mi < 4; ++mi) {
        #pragma unroll
        for (int j = 0; j < 4; ++j) {
            int row = m0 + wr * 64 + mi * 16 + lk * 4 + j;
            float* orow = out + (size_t)row * NE + e0 + wc * 64 + lr;
            #pragma unroll
            for (int ni = 0; ni < 4; ++ni)
                orow[ni * 16] = acc[mi][ni][j] + biasv[ni];
        }
    }
}

// =====================================================================
// FALLBACK (ws too small for two-pass): R6 fused kernel, 78 us proven.
// =====================================================================
__global__ __launch_bounds__(256) void convert_w_row(
    const float* __restrict__ pw, unsigned char* __restrict__ wsb)
{
    int id = blockIdx.x * 256 + threadIdx.x;   // 768*96 = 73728
    int e  = id / 96;
    int ck = id - e * 96;
    int k0 = ck * 8;

    const float4 f0 = *reinterpret_cast<const float4*>(pw + (size_t)e * KDIM + k0);
    const float4 f1 = *reinterpret_cast<const float4*>(pw + (size_t)e * KDIM + k0 + 4);
    int bn = e >> 8;
    int r  = e & 255;
    int kk = k0 >> 6;
    int ch = (k0 & 63) >> 3;
    size_t off = (size_t)(bn * NKK + kk) * TILE_B_BYTES + r * 128
               + ((ch ^ (r & 7)) * 16);
    *reinterpret_cast<uint4*>(wsb + off) = make_uint4(
        cvtpk(f0.x, f0.y), cvtpk(f0.z, f0.w),
        cvtpk(f1.x, f1.y), cvtpk(f1.z, f1.w));
}

template <bool WSB>
__global__ __launch_bounds__(512, 4) void fused_gemm(
    const float* __restrict__ x,
    const int* __restrict__ start_h,
    const int* __restrict__ start_w,
    const float* __restrict__ pw,
    const float* __restrict__ pb,
    const unsigned char* __restrict__ wsb,
    float* __restrict__ out)
{
    __shared__ __align__(16) unsigned short lA[2][BM * BK];
    __shared__ __align__(16) unsigned short lB[BN * BK];
    __shared__ int baseOff[BM];

    const int tid = threadIdx.x;
    const int bid  = blockIdx.x;
    const int lbid = (bid & 7) * (NWG / 8) + (bid >> 3);
    const int bm = lbid / NBLK_N;
    const int bn = lbid - bm * NBLK_N;
    const int m0 = bm * BM;
    const int e0 = bn * BN;

    if (tid < BM) {
        int m = m0 + tid;
        int b = m / NPATCH;
        int n = m - b * NPATCH;
        baseOff[tid] = b * (NC * HW) + start_h[b * NPATCH + n] * NW
                     + start_w[b * NPATCH + n];
    }

    const int lane = tid & 63;
    const int wv   = tid >> 6;
    const int wr   = wv >> 2;
    const int wc   = wv & 3;
    const int lr   = lane & 15;
    const int lk   = lane >> 4;

    const int rt = tid >> 4;
    const int j0 = (tid & 15) * 4;
    const int chunk  = j0 >> 3;
    const int within = j0 & 7;
    const int hsub   = j0 >> 4;
    const int wsub   = j0 & 15;

    __syncthreads();

    int ab[4];
    #pragma unroll
    for (int i = 0; i < 4; ++i)
        ab[i] = baseOff[i * 32 + rt] + hsub * NW + wsub;

    f32x4 acc[4][4] = {};
    float4 ar[4];

#define LOADA(KK)                                                             \
    {                                                                         \
        const int koff = ((KK) >> 2) * HW + ((KK) & 3) * 4 * NW;              \
        _Pragma("unroll")                                                     \
        for (int i = 0; i < 4; ++i)                                           \
            ar[i] = *reinterpret_cast<const float4*>(x + ab[i] + koff);       \
    }

#define WRITEA(BUF)                                                           \
    {                                                                         \
        _Pragma("unroll")                                                     \
        for (int i = 0; i < 4; ++i) {                                         \
            int r = i * 32 + rt;                                              \
            int off = r * BK + ((chunk ^ (r & 7)) * 8) + within;              \
            *reinterpret_cast<uint2*>(&lA[BUF][off]) =                        \
                make_uint2(cvtpk(ar[i].x, ar[i].y), cvtpk(ar[i].z, ar[i].w)); \
        }                                                                     \
    }

#define STAGEB(KK)                                                            \
    if (WSB) {                                                                \
        const unsigned char* src = wsb + (size_t)(bn * NKK + (KK)) * TILE_B_BYTES \
                                 + wv * 1024 + lane * 16;                     \
        unsigned char* dst = reinterpret_cast<unsigned char*>(lB) + wv * 1024;\
        _Pragma("unroll")                                                     \
        for (int i = 0; i < 4; ++i)                                           \
            gload_lds16(src + i * 8192, dst + i * 8192);                      \
    } else {                                                                  \
        _Pragma("unroll")                                                     \
        for (int i = 0; i < 8; ++i) {                                         \
            int r = i * 32 + rt;                                              \
            const float4 wf = *reinterpret_cast<const float4*>(               \
                pw + (size_t)(e0 + r) * KDIM + (KK) * BK + j0);               \
            int off = r * BK + ((chunk ^ (r & 7)) * 8) + within;              \
            *reinterpret_cast<uint2*>(&lB[off]) =                            \
                make_uint2(cvtpk(wf.x, wf.y), cvtpk(wf.z, wf.w));             \
        }                                                                     \
    }

#define COMPUTE(BUF)                                                          \
    {                                                                         \
        _Pragma("unroll")                                                     \
        for (int ks = 0; ks < 2; ++ks) {                                      \
            short8 af[4], bfr[4];                                             \
            _Pragma("unroll")                                                 \
            for (int mi = 0; mi < 4; ++mi) {                                  \
                int row = wr * 64 + mi * 16 + lr;                             \
                int off = row * BK + (((ks * 4 + lk) ^ (row & 7)) * 8);       \
                af[mi] = *reinterpret_cast<const short8*>(&lA[BUF][off]);     \
            }                                                                 \
            _Pragma("unroll")                                                 \
            for (int ni = 0; ni < 4; ++ni) {                                  \
                int row = wc * 64 + ni * 16 + lr;                             \
                int off = row * BK + (((ks * 4 + lk) ^ (row & 7)) * 8);       \
                bfr[ni] = *reinterpret_cast<const short8*>(&lB[off]);         \
            }                                                                 \
            _Pragma("unroll")                                                 \
            for (int mi = 0; mi < 4; ++mi)                                    \
                _Pragma("unroll")                                             \
                for (int ni = 0; ni < 4; ++ni)                                \
                    acc[mi][ni] = __builtin_amdgcn_mfma_f32_16x16x32_bf16(    \
                        af[mi], bfr[ni], acc[mi][ni], 0, 0, 0);               \
        }                                                                     \
    }

    LOADA(0)
    WRITEA(0)
    STAGEB(0)
    __syncthreads();

    for (int kk = 0; kk < NKK; ++kk) {
        const int buf = kk & 1;
        if (kk + 1 < NKK) LOADA(kk + 1)
        COMPUTE(buf)
        __syncthreads();
        if (kk + 1 < NKK) {
            WRITEA(buf ^ 1)
            STAGEB(kk + 1)
        }
        __syncthreads();
    }

#undef LOADA
#undef WRITEA
#undef STAGEB
#undef COMPUTE

    float biasv[4];
    #pragma unroll
    for (int ni = 0; ni < 4; ++ni)
        biasv[ni] = pb[e0 + wc * 64 + ni * 16 + lr];

    #pragma unroll
    for (int mi = 0; mi < 4; ++mi) {
        #pragma unroll
        for (int j = 0; j < 4; ++j) {
            int row = m0 + wr * 64 + mi * 16 + lk * 4 + j;
            float* orow = out + (size_t)row * NE + e0 + wc * 64 + lr;
            #pragma unroll
            for (int ni = 0; ni < 4; ++ni)
                orow[ni * 16] = acc[mi][ni][j] + biasv[ni];
        }
    }
}

extern "C" void kernel_launch(void* const* d_in, const int* in_sizes, int n_in,
                              void* d_out, int out_size, void* d_ws, size_t ws_size,
                              hipStream_t stream) {
    const float* x  = (const float*)d_in[0];
    const int* sh   = (const int*)d_in[1];
    const int* sw   = (const int*)d_in[2];
    const float* pw = (const float*)d_in[3];
    const float* pb = (const float*)d_in[4];
    float* out = (float*)d_out;

    if (ws_size >= WS_A_BYTES + WS_B_BYTES) {
        unsigned char* wsa = (unsigned char*)d_ws;
        unsigned char* wsb = wsa + WS_A_BYTES;
        hipLaunchKernelGGL(gather_a, dim3(MDIM * 96 / 256), dim3(256), 0, stream,
                           x, sh, sw, wsa);
        hipLaunchKernelGGL(convert_w_frag, dim3(288), dim3(256), 0, stream, pw, wsb);
        hipLaunchKernelGGL(gemm2, dim3(NWG), dim3(512), 0, stream,
                           wsa, wsb, pb, out);
    } else if (ws_size >= WS_B_BYTES) {
        unsigned char* wsb = (unsigned char*)d_ws;
        hipLaunchKernelGGL(convert_w_row, dim3(288), dim3(256), 0, stream, pw, wsb);
        hipLaunchKernelGGL(fused_gemm<true>, dim3(NWG), dim3(512), 0, stream,
                           x, sh, sw, pw, pb, wsb, out);
    } else {
        hipLaunchKernelGGL(fused_gemm<false>, dim3(NWG), dim3(512), 0, stream,
                           x, sh, sw, pw, pb, (const unsigned char*)nullptr, out);
    }
}